// Round 14
// baseline (1092.760 us; speedup 1.0000x reference)
//
#include <hip/hip_runtime.h>
#include <math.h>

// Problem constants
#define Bn   8
#define Nn   2048
#define Dn   192
#define Gn   512
#define Sn   32
#define OUTn 384
#define Mrows (Bn * Gn * Sn)

// megakernel block ranges
#define NB_FPS   8
#define NB_PREP  1680
#define NB_KNN   1024
#define NB_G1    3072          // 1024 bm x 3 bn
#define BLK_PREP (NB_FPS)                      // 8
#define BLK_KNN  (NB_FPS + NB_PREP)            // 1688
#define BLK_G1   (NB_FPS + NB_PREP + NB_KNN)   // 2712

typedef __attribute__((ext_vector_type(8))) unsigned short ushortx8;
typedef __attribute__((ext_vector_type(8))) __bf16 bf16x8;
typedef __attribute__((ext_vector_type(4))) float floatx4;

// ---------- ws layout (bytes) ----------
static constexpr size_t OFF_KNN    = 0;                    // 131072 * 4
static constexpr size_t OFF_CIDX   = 524288;               // 4096 * 4
static constexpr size_t OFF_DIFF   = 540672;               // 393216 * 4
static constexpr size_t OFF_SUMS   = 2113536;              // 2 doubles
static constexpr size_t OFF_STD    = 2113552;              // 1 u32 (1/std bits, 0xFF sentinel)
static constexpr size_t OFF_CNT    = 2113568;              // 1 int (knn done counter)
static constexpr size_t OFF_PCNT   = 2113572;              // 1 int (prep done counter)
static constexpr size_t OFF_DENOM  = 2113792;              // 64 floats (1/denom)
static constexpr size_t OFF_W1B    = 2114048;              // 147456 * 2
static constexpr size_t OFF_WAB    = 2408960;              // 73728 * 2
static constexpr size_t OFF_WBB    = 2556416;              // 73728 * 2
static constexpr size_t OFF_G1     = 2703872;              // 50331648 * 2
static constexpr size_t OFF_FEATB  = 103367168;            // 3145728 * 2 (bf16 feats)
static constexpr size_t OFF_CSTAGE = 109658624;            // 12288 * 4 (centers, 0xFF sentinel)
static constexpr size_t OFF_GFLAG  = 109707776;            // 4096 * 4 (knn group flags, 0)

__device__ __forceinline__ unsigned short f2bf(float f) {
  unsigned u = __float_as_uint(f);
  unsigned r = (u + 0x7FFFu + ((u >> 16) & 1u)) >> 16;   // RNE
  return (unsigned short)r;
}
__device__ __forceinline__ float bf2f(unsigned short h) {
  return __uint_as_float(((unsigned)h) << 16);
}
__device__ __forceinline__ floatx4 mfma_bf16(ushortx8 a, ushortx8 b, floatx4 c) {
  return __builtin_amdgcn_mfma_f32_16x16x32_bf16(
      __builtin_bit_cast(bf16x8, a), __builtin_bit_cast(bf16x8, b), c, 0, 0, 0);
}
__device__ __forceinline__ void gld16(const void* g, void* l) {
  __builtin_amdgcn_global_load_lds(
      (const __attribute__((address_space(1))) unsigned int*)g,
      (__attribute__((address_space(3))) unsigned int*)l, 16, 0, 0);
}
template <int CTRL>
__device__ __forceinline__ float dpp_max(float v) {
  int o = __builtin_amdgcn_update_dpp(0, __float_as_int(v), CTRL, 0xf, 0xf, true);
  return fmaxf(v, __int_as_float(o));
}
__device__ __forceinline__ void ast_u32(unsigned* p, unsigned v) {
  __hip_atomic_store(p, v, __ATOMIC_RELAXED, __HIP_MEMORY_SCOPE_AGENT);
}
__device__ __forceinline__ void ast_f32(float* p, float v) {
  __hip_atomic_store(p, v, __ATOMIC_RELAXED, __HIP_MEMORY_SCOPE_AGENT);
}
__device__ __forceinline__ unsigned ald_u32(const unsigned* p) {
  return __hip_atomic_load(p, __ATOMIC_RELAXED, __HIP_MEMORY_SCOPE_AGENT);
}

// ---------------------------------------------------------------------------
// MEGAKERNEL: fps (0-7) + prep (8..1687) + knn (1688..2711) + gemm1 (2712..
// 5783), all overlapped via agent-scope sentinel/flag protocols (G16):
//  - prep: bf16 conversions written as agent u32 atomic stores (write-through
//    to coherent point; consumers' L2s untouched pre-acquire -> fresh fetch);
//    release-counted into PCNT.
//  - fps: r5/r10-proven shape (256 thr, 8 pts/lane, LDS-staged VGPR-resident
//    points, VGPR=52). Publishes centers to CSTAGE (sentinel protocol, r13).
//  - knn: spins on its center, computes, publishes knn/diffb (line-exclusive)
//    + cidx via agent stores, RELEASE group flag; last block computes 1/std
//    into a sentinel word.
//  - gemm1: acquire PCNT -> acquire its 4 group flags -> mainloop (unchanged
//    r8 structure) -> acquire 1/std sentinel -> epilogue.
// Deadlock-free under in-order dispatch (spinners wait only on earlier
// blocks — assumption already validated by r13's fused front).
// All arithmetic bit-identical to prior rounds.
// ---------------------------------------------------------------------------
__global__ __launch_bounds__(256) void mega_kernel(
    const float* __restrict__ points, float* __restrict__ centers,
    const float* __restrict__ W1, const float* __restrict__ Wa,
    const float* __restrict__ Wb, const float* __restrict__ feats,
    const float* __restrict__ b1,
    unsigned short* __restrict__ W1b, unsigned short* __restrict__ Wab,
    unsigned short* __restrict__ Wbb, unsigned short* __restrict__ featb,
    float* __restrict__ rdenomTab, float* __restrict__ cstage,
    int* __restrict__ knn, int* __restrict__ cidx, float* __restrict__ diffb,
    double* __restrict__ sums, int* __restrict__ cnt, unsigned* __restrict__ stdbits,
    unsigned* __restrict__ pcnt, unsigned* __restrict__ gflag,
    unsigned short* __restrict__ G1) {
  const int t = threadIdx.x;
  const int w = t >> 6, lane = t & 63;
  const int blk = blockIdx.x;
  __shared__ __align__(16) char smem[32832];

  // ======================= PREP path =======================
  if (blk >= BLK_PREP && blk < BLK_KNN) {
    unsigned* W1b32 = (unsigned*)W1b;
    unsigned* Wab32 = (unsigned*)Wab;
    unsigned* Wbb32 = (unsigned*)Wbb;
    unsigned* fb32  = (unsigned*)featb;
    const int base = (blk - BLK_PREP) * 1024 + t;
#pragma unroll
    for (int j = 0; j < 4; ++j) {
      const int i = base + j * 256;     // u32 index, < 1720320 by grid
      const float* src; unsigned* dst; int k;
      if (i < 73728)       { src = W1;    dst = W1b32; k = i; }
      else if (i < 110592) { src = Wa;    dst = Wab32; k = i - 73728; }
      else if (i < 147456) { src = Wb;    dst = Wbb32; k = i - 110592; }
      else                 { src = feats; dst = fb32;  k = i - 147456; }
      const unsigned lo = f2bf(src[2 * k]);
      const unsigned hi = f2bf(src[2 * k + 1]);
      ast_u32(dst + k, lo | (hi << 16));
    }
    if (blk == BLK_PREP && t < 64)
      ast_f32(rdenomTab + t, (float)(1.0 / pow(1000.0, (double)t / 64.0)));
    __syncthreads();
    if (t == 0) {
      __threadfence();
      __hip_atomic_fetch_add(pcnt, 1u, __ATOMIC_RELEASE, __HIP_MEMORY_SCOPE_AGENT);
    }
    return;
  }

  // ======================= KNN path =======================
  if (blk >= BLK_KNN && blk < BLK_G1) {
    const int bg = (blk - BLK_KNN) * 4 + w;
    const int b = bg >> 9;
    const float* P = points + (size_t)b * Nn * 3;
    const unsigned* cs = (const unsigned*)(cstage + (size_t)bg * 3);

    unsigned ux, uy, uz;
    for (;;) {
      ux = ald_u32(cs + 0); uy = ald_u32(cs + 1); uz = ald_u32(cs + 2);
      if (ux != 0xFFFFFFFFu && uy != 0xFFFFFFFFu && uz != 0xFFFFFFFFu) break;
      __builtin_amdgcn_s_sleep(16);
    }
    const float cx = __uint_as_float(ux);
    const float cy = __uint_as_float(uy);
    const float cz = __uint_as_float(uz);
    const float aa = __fadd_rn(__fadd_rn(__fmul_rn(cx, cx), __fmul_rn(cy, cy)), __fmul_rn(cz, cz));

    unsigned key[32];
#pragma unroll 8
    for (int s = 0; s < 32; ++s) {
      const int n = s * 64 + lane;
      float X = P[n * 3], Y = P[n * 3 + 1], Z = P[n * 3 + 2];
      float bbv = __fadd_rn(__fadd_rn(__fmul_rn(X, X), __fmul_rn(Y, Y)), __fmul_rn(Z, Z));
      float dot = __fadd_rn(__fadd_rn(__fmul_rn(cx, X), __fmul_rn(cy, Y)), __fmul_rn(cz, Z));
      float d2 = __fsub_rn(__fadd_rn(aa, bbv), __fmul_rn(2.0f, dot));
      unsigned u = __float_as_uint(d2);
      key[s] = u ^ ((unsigned)((int)u >> 31) | 0x80000000u);
    }
    unsigned mk = key[0]; int ms = 0;
#pragma unroll
    for (int s = 1; s < 32; ++s)
      if (key[s] < mk) { mk = key[s]; ms = s; }

    int mysel = 0;
    for (int it = 0; it < Sn; ++it) {
      unsigned long long p = ((unsigned long long)mk << 32) | (unsigned)(ms * 64 + lane);
#pragma unroll
      for (int off = 1; off <= 32; off <<= 1) {
        unsigned long long o = __shfl_xor(p, off, 64);
        p = (o < p) ? o : p;
      }
      const int n_win = (int)(unsigned)p;
      if (lane == it) mysel = n_win;
      if (lane == (n_win & 63)) {
        const int sw = n_win >> 6;
#pragma unroll
        for (int s = 0; s < 32; ++s)
          if (s == sw) key[s] = 0xFFFFFFFFu;
        mk = key[0]; ms = 0;
#pragma unroll
        for (int s = 1; s < 32; ++s)
          if (key[s] < mk) { mk = key[s]; ms = s; }
      }
    }

    double s1 = 0.0, s2 = 0.0;
    if (lane < Sn) {
      ast_u32((unsigned*)&knn[(size_t)bg * Sn + lane], (unsigned)mysel);
      float X = P[mysel * 3], Y = P[mysel * 3 + 1], Z = P[mysel * 3 + 2];
      float dx = __fsub_rn(X, cx), dy = __fsub_rn(Y, cy), dz = __fsub_rn(Z, cz);
      float* db = diffb + (size_t)bg * 96 + lane * 3;
      ast_f32(db + 0, dx); ast_f32(db + 1, dy); ast_f32(db + 2, dz);
      s1 = (double)dx + (double)dy + (double)dz;
      s2 = (double)dx * (double)dx + (double)dy * (double)dy + (double)dz * (double)dz;
    }
#pragma unroll
    for (int off = 1; off <= 32; off <<= 1) {
      s1 += __shfl_xor(s1, off, 64);
      s2 += __shfl_xor(s2, off, 64);
    }
    if (lane == 0) {
      ast_u32((unsigned*)&cidx[bg], (unsigned)__shfl(mysel, 0, 64));
      atomicAdd(sums, s1);
      atomicAdd(sums + 1, s2);
      // RELEASE: wave-wide vmcnt drain orders all this wave's stores first
      __hip_atomic_store(&gflag[bg], 1u, __ATOMIC_RELEASE, __HIP_MEMORY_SCOPE_AGENT);
    }
    __threadfence();
    __syncthreads();
    if (t == 0) {
      const int old = atomicAdd(cnt, 1);
      if (old == NB_KNN - 1) {          // last knn block: publish 1/(std+eps)
        __threadfence();
        const double S1 = atomicAdd(sums, 0.0);
        const double S2 = atomicAdd(sums + 1, 0.0);
        const double n = (double)(Bn * Gn * Sn * 3);
        const double mean = S1 / n;
        const double var = (S2 - S1 * mean) / (n - 1.0);
        const float stdf = (float)sqrt(var) + 1e-5f;
        const float rstdv = (float)(1.0 / (double)stdf);
        __hip_atomic_store(stdbits, __float_as_uint(rstdv), __ATOMIC_RELEASE,
                           __HIP_MEMORY_SCOPE_AGENT);
      }
    }
    return;
  }

  // ======================= GEMM1 path =======================
  if (blk >= BLK_G1) {
    const int gb = blk - BLK_G1;
    const int bm = gb & 1023, bn = gb >> 10;
    unsigned short* As = (unsigned short*)smem;
    unsigned short* Bs = (unsigned short*)(smem + 16384);
    const int wid = w, quad = lane >> 4, c16 = lane & 15;
    const int wr = wid >> 1, wc = wid & 1;

    // wait for prep (weights/feats/rdenom published)
    while (__hip_atomic_load(pcnt, __ATOMIC_ACQUIRE, __HIP_MEMORY_SCOPE_AGENT) <
           (unsigned)NB_PREP)
      __builtin_amdgcn_s_sleep(32);
    // wait for this block's 4 knn groups
#pragma unroll
    for (int g = 0; g < 4; ++g)
      while (__hip_atomic_load(&gflag[bm * 4 + g], __ATOMIC_ACQUIRE,
                               __HIP_MEMORY_SCOPE_AGENT) == 0u)
        __builtin_amdgcn_s_sleep(16);

    int aOffN[4], aOffC[4], bOff[4];
#pragma unroll
    for (int i = 0; i < 4; ++i) {
      const int slot = i * 256 + t;
      const int row = slot >> 3, segV = slot & 7;
      const int seg = segV ^ (row & 7);
      const int grow = bm * 128 + row;
      const int bg = grow >> 5, s = grow & 31, bb_ = bg >> 9;
      const int nidx = knn[(size_t)bg * Sn + s];          // line-exclusive, post-acquire
      const int ci = (int)ald_u32((const unsigned*)&cidx[bg]);  // shared line -> atomic
      aOffN[i] = (bb_ * Nn + nidx) * Dn + seg * 8;
      aOffC[i] = (bb_ * Nn + ci) * Dn + seg * 8;
      bOff[i] = (bn * 128 + row) * 384 + seg * 8;
    }

    floatx4 acc[4][4];
#pragma unroll
    for (int i = 0; i < 4; ++i)
#pragma unroll
      for (int j = 0; j < 4; ++j) acc[i][j] = (floatx4){0.f, 0.f, 0.f, 0.f};

    for (int kt = 0; kt < 6; ++kt) {
      const int kb = kt * 64;
#pragma unroll
      for (int i = 0; i < 4; ++i) {
        const unsigned short* srcA =
            (kt < 3) ? (featb + aOffN[i] + kb) : (featb + aOffC[i] + (kb - 192));
        gld16(srcA, &As[(i * 256 + wid * 64) * 8]);
        gld16(W1b + bOff[i] + kb, &Bs[(i * 256 + wid * 64) * 8]);
      }
      __syncthreads();
#pragma unroll
      for (int ks = 0; ks < 2; ++ks) {
        ushortx8 af[4], bf[4];
#pragma unroll
        for (int mt = 0; mt < 4; ++mt) {
          const int row = wr * 64 + mt * 16 + c16;
          const int seg = (ks * 4 + quad) ^ (row & 7);
          af[mt] = *(const ushortx8*)&As[row * 64 + seg * 8];
        }
#pragma unroll
        for (int nt = 0; nt < 4; ++nt) {
          const int row = wc * 64 + nt * 16 + c16;
          const int seg = (ks * 4 + quad) ^ (row & 7);
          bf[nt] = *(const ushortx8*)&Bs[row * 64 + seg * 8];
        }
#pragma unroll
        for (int mt = 0; mt < 4; ++mt)
#pragma unroll
          for (int nt = 0; nt < 4; ++nt)
            acc[mt][nt] = mfma_bf16(af[mt], bf[nt], acc[mt][nt]);
      }
      __syncthreads();
    }

    // wait for 1/std (published by last knn block)
    unsigned sb;
    for (;;) {
      sb = __hip_atomic_load(stdbits, __ATOMIC_ACQUIRE, __HIP_MEMORY_SCOPE_AGENT);
      if (sb != 0xFFFFFFFFu) break;
      __builtin_amdgcn_s_sleep(16);
    }
    const float rstd = __uint_as_float(sb);

    float bias[4], rdnm[4];
    bool usin[4];
#pragma unroll
    for (int nt = 0; nt < 4; ++nt) {
      const int col = bn * 128 + wc * 64 + nt * 16 + c16;
      bias[nt] = b1[col];
      const int j = col & 127;
      usin[nt] = (j < 64);
      rdnm[nt] = rdenomTab[j & 63];
    }
#pragma unroll
    for (int mt = 0; mt < 4; ++mt) {
#pragma unroll
      for (int r = 0; r < 4; ++r) {
        const int row = bm * 128 + wr * 64 + mt * 16 + quad * 4 + r;
        const float dv = diffb[(size_t)row * 3 + bn];   // line-exclusive, post-acquire
        const float x = __fmul_rn(dv, rstd);
        const float zb = __fmul_rn(100.0f, x);
#pragma unroll
        for (int nt = 0; nt < 4; ++nt) {
          const int col = bn * 128 + wc * 64 + nt * 16 + c16;
          float y = fmaxf(acc[mt][nt][r] + bias[nt], 0.f);
          float z = __fmul_rn(zb, rdnm[nt]);
          float p = usin[nt] ? __sinf(z) : __cosf(z);
          float g = (y + p) * p;
          G1[(size_t)row * 384 + col] = f2bf(g);
        }
      }
    }
    return;
  }

  // ======================= FPS path (blocks 0-7) =======================
  const int b = blk;
  float4* p4 = (float4*)smem;
  unsigned long long* wkey = (unsigned long long*)(smem + 32768);  // [2][4]

  const float* P = points + (size_t)b * Nn * 3;
  for (int n = t; n < Nn; n += 256) {
    float x = P[n * 3], y = P[n * 3 + 1], z = P[n * 3 + 2];
    p4[n] = make_float4(x, y, z, 0.f);
  }
  __syncthreads();

  float rx[8], ry[8], rz[8], dist[8];
#pragma unroll
  for (int k = 0; k < 8; ++k) {
    float4 p = p4[t * 8 + k];       // LDS source -> VGPR-resident (r5/r10/r12)
    rx[k] = p.x; ry[k] = p.y; rz[k] = p.z;
    dist[k] = INFINITY;
  }

  int cur = 0;
  for (int it = 0; it < Gn; ++it) {
    const float4 c = p4[cur];
    if (t == 0) {
      float* cd = centers + ((size_t)b * Gn + it) * 3;
      cd[0] = c.x; cd[1] = c.y; cd[2] = c.z;
      unsigned* cs = (unsigned*)(cstage + ((size_t)b * Gn + it) * 3);
      ast_u32(cs + 0, __float_as_uint(c.x));
      ast_u32(cs + 1, __float_as_uint(c.y));
      ast_u32(cs + 2, __float_as_uint(c.z));
    }
    float bv = -1.0f;
#pragma unroll
    for (int k = 0; k < 8; ++k) {
      float dx = __fsub_rn(rx[k], c.x);
      float dy = __fsub_rn(ry[k], c.y);
      float dz = __fsub_rn(rz[k], c.z);
      float d = __fadd_rn(__fadd_rn(__fmul_rn(dx, dx), __fmul_rn(dy, dy)), __fmul_rn(dz, dz));
      dist[k] = fminf(dist[k], d);
      bv = fmaxf(bv, dist[k]);
    }
    int li = 7;
#pragma unroll
    for (int k = 6; k >= 0; --k) li = (dist[k] == bv) ? k : li;

    float red = bv;
    red = dpp_max<0x111>(red);
    red = dpp_max<0x112>(red);
    red = dpp_max<0x114>(red);
    red = dpp_max<0x118>(red);
    red = dpp_max<0x142>(red);
    red = dpp_max<0x143>(red);
    const float M = __int_as_float(__builtin_amdgcn_readlane(__float_as_int(red), 63));

    unsigned long long msk = __ballot(bv == M);
    const int L = __ffsll((long long)msk) - 1;
    const int liL = __builtin_amdgcn_readlane(li, L);
    const int idx = (w * 64 + L) * 8 + liL;

    unsigned long long key =
        ((unsigned long long)__float_as_uint(M) << 32) | (unsigned)(0x7FFFFFFF - idx);
    if (lane == 0) wkey[(it & 1) * 4 + w] = key;
    __syncthreads();
    unsigned long long k0 = wkey[(it & 1) * 4 + 0];
    unsigned long long k1 = wkey[(it & 1) * 4 + 1];
    unsigned long long k2 = wkey[(it & 1) * 4 + 2];
    unsigned long long k3 = wkey[(it & 1) * 4 + 3];
    unsigned long long m01 = (k1 > k0) ? k1 : k0;
    unsigned long long m23 = (k3 > k2) ? k3 : k2;
    unsigned long long mm = (m23 > m01) ? m23 : m01;
    cur = 0x7FFFFFFF - (int)(unsigned)mm;
  }
}

// ===========================================================================
// GEMM23 (fused residual block) — r9-measured version, unchanged.
// ===========================================================================
__global__ __launch_bounds__(512) void gemm23_kernel(
    const unsigned short* __restrict__ G1, const unsigned short* __restrict__ Wab,
    const float* __restrict__ ba, const unsigned short* __restrict__ Wbb,
    const float* __restrict__ bb, float* __restrict__ outp) {
  __shared__ __align__(16) char smem[100352];
  unsigned short* Htile = (unsigned short*)smem;                  // 128 x 200
  unsigned short* As    = (unsigned short*)(smem + 51200);        // 128 x 64
  unsigned short* BsA   = (unsigned short*)(smem + 51200 + 16384);// 192 x 64
  unsigned short* BsB   = (unsigned short*)(smem + 51200);        // 384 x 64 (aliases)

  const int t = threadIdx.x;
  const int bm = blockIdx.x;
  const int lane = t & 63, quad = lane >> 4, c16 = lane & 15;
  const int wid = t >> 6;
  const int wr = wid >> 2, wc = wid & 3;    // 2 x 4 wave grid

  int aOff[2], bOffA[3];
#pragma unroll
  for (int i = 0; i < 2; ++i) {
    const int slot = i * 512 + t;
    const int row = slot >> 3, segV = slot & 7;
    aOff[i] = (bm * 128 + row) * 384 + (segV ^ (row & 7)) * 8;
  }
#pragma unroll
  for (int i = 0; i < 3; ++i) {
    const int slot = i * 512 + t;
    const int row = slot >> 3, segV = slot & 7;
    bOffA[i] = row * 384 + (segV ^ (row & 7)) * 8;
  }

  floatx4 accA[4][3];
#pragma unroll
  for (int i = 0; i < 4; ++i)
#pragma unroll
    for (int j = 0; j < 3; ++j) accA[i][j] = (floatx4){0.f, 0.f, 0.f, 0.f};

  for (int kt = 0; kt < 6; ++kt) {
    const int kb = kt * 64;
#pragma unroll
    for (int i = 0; i < 2; ++i) gld16(G1 + aOff[i] + kb, As + ((size_t)(i * 512 + t)) * 8);
#pragma unroll
    for (int i = 0; i < 3; ++i) gld16(Wab + bOffA[i] + kb, BsA + ((size_t)(i * 512 + t)) * 8);
    __syncthreads();
#pragma unroll
    for (int ks = 0; ks < 2; ++ks) {
      ushortx8 af[4], bf[3];
#pragma unroll
      for (int mt = 0; mt < 4; ++mt) {
        const int row = wr * 64 + mt * 16 + c16;
        const int seg = (ks * 4 + quad) ^ (row & 7);
        af[mt] = *(const ushortx8*)&As[row * 64 + seg * 8];
      }
#pragma unroll
      for (int nt = 0; nt < 3; ++nt) {
        const int row = wc * 48 + nt * 16 + c16;
        const int seg = (ks * 4 + quad) ^ (row & 7);
        bf[nt] = *(const ushortx8*)&BsA[row * 64 + seg * 8];
      }
#pragma unroll
      for (int mt = 0; mt < 4; ++mt)
#pragma unroll
        for (int nt = 0; nt < 3; ++nt)
          accA[mt][nt] = mfma_bf16(af[mt], bf[nt], accA[mt][nt]);
    }
    __syncthreads();
  }

#pragma unroll
  for (int nt = 0; nt < 3; ++nt) {
    const int col = wc * 48 + nt * 16 + c16;
    const float bias = ba[col];
#pragma unroll
    for (int mt = 0; mt < 4; ++mt)
#pragma unroll
      for (int r = 0; r < 4; ++r) {
        const int row = wr * 64 + mt * 16 + quad * 4 + r;
        Htile[row * 200 + col] = f2bf(fmaxf(accA[mt][nt][r] + bias, 0.f));
      }
  }
  __syncthreads();

  int bOffB[6];
#pragma unroll
  for (int i = 0; i < 6; ++i) {
    const int slot = i * 512 + t;
    const int row = slot >> 3, segV = slot & 7;
    bOffB[i] = row * 192 + (segV ^ (row & 7)) * 8;
  }

  floatx4 acc[4][6];
#pragma unroll
  for (int i = 0; i < 4; ++i)
#pragma unroll
    for (int j = 0; j < 6; ++j) acc[i][j] = (floatx4){0.f, 0.f, 0.f, 0.f};

  for (int kt = 0; kt < 3; ++kt) {
    const int kb = kt * 64;
#pragma unroll
    for (int i = 0; i < 6; ++i) gld16(Wbb + bOffB[i] + kb, BsB + ((size_t)(i * 512 + t)) * 8);
    __syncthreads();
#pragma unroll
    for (int ks = 0; ks < 2; ++ks) {
      ushortx8 af[4], bf[6];
#pragma unroll
      for (int mt = 0; mt < 4; ++mt) {
        const int row = wr * 64 + mt * 16 + c16;
        af[mt] = *(const ushortx8*)&Htile[row * 200 + kb + ks * 32 + quad * 8];
      }
#pragma unroll
      for (int nt = 0; nt < 6; ++nt) {
        const int row = wc * 96 + nt * 16 + c16;
        const int seg = (ks * 4 + quad) ^ (row & 7);
        bf[nt] = *(const ushortx8*)&BsB[row * 64 + seg * 8];
      }
#pragma unroll
      for (int mt = 0; mt < 4; ++mt)
#pragma unroll
        for (int nt = 0; nt < 6; ++nt)
          acc[mt][nt] = mfma_bf16(af[mt], bf[nt], acc[mt][nt]);
    }
    __syncthreads();
  }

#pragma unroll
  for (int nt = 0; nt < 6; ++nt) {
    const int col = wc * 96 + nt * 16 + c16;
    const float bias = bb[col];
    float gmax[2] = {-INFINITY, -INFINITY};
    float gsum[2] = {0.f, 0.f};
#pragma unroll
    for (int mt = 0; mt < 4; ++mt) {
      const int grp = mt >> 1;
#pragma unroll
      for (int r = 0; r < 4; ++r) {
        const int row = bm * 128 + wr * 64 + mt * 16 + quad * 4 + r;
        float v = acc[mt][nt][r] + bias + bf2f(G1[(size_t)row * 384 + col]);
        v = fmaxf(v, 0.f);
        gmax[grp] = fmaxf(gmax[grp], v);
        gsum[grp] += v;
      }
    }
#pragma unroll
    for (int grp = 0; grp < 2; ++grp) {
      float m = gmax[grp], su = gsum[grp];
#pragma unroll
      for (int off = 16; off <= 32; off <<= 1) {
        m = fmaxf(m, __shfl_xor(m, off, 64));
        su += __shfl_xor(su, off, 64);
      }
      if (quad == 0) {
        const int bg = bm * 4 + wr * 2 + grp;
        outp[(size_t)bg * 384 + col] = m + su / 32.0f;
      }
    }
  }
}

// ---------------------------------------------------------------------------
extern "C" void kernel_launch(void* const* d_in, const int* in_sizes, int n_in,
                              void* d_out, int out_size, void* d_ws, size_t ws_size,
                              hipStream_t stream) {
  const float* points = (const float*)d_in[0];
  const float* feats  = (const float*)d_in[1];
  const float* W1 = (const float*)d_in[2];
  const float* b1 = (const float*)d_in[3];
  const float* Wa = (const float*)d_in[4];
  const float* ba = (const float*)d_in[5];
  const float* Wb = (const float*)d_in[6];
  const float* bb = (const float*)d_in[7];
  float* outF = (float*)d_out;

  char* ws = (char*)d_ws;
  int*            knn      = (int*)(ws + OFF_KNN);
  int*            cidx     = (int*)(ws + OFF_CIDX);
  float*          diffb    = (float*)(ws + OFF_DIFF);
  double*         sums     = (double*)(ws + OFF_SUMS);
  unsigned*       stdbits  = (unsigned*)(ws + OFF_STD);
  int*            cnt      = (int*)(ws + OFF_CNT);
  unsigned*       pcnt     = (unsigned*)(ws + OFF_PCNT);
  float*          rdenomTab= (float*)(ws + OFF_DENOM);
  unsigned short* W1b      = (unsigned short*)(ws + OFF_W1B);
  unsigned short* Wab      = (unsigned short*)(ws + OFF_WAB);
  unsigned short* Wbb      = (unsigned short*)(ws + OFF_WBB);
  unsigned short* G1       = (unsigned short*)(ws + OFF_G1);
  unsigned short* featb    = (unsigned short*)(ws + OFF_FEATB);
  float*          cstage   = (float*)(ws + OFF_CSTAGE);
  unsigned*       gflag    = (unsigned*)(ws + OFF_GFLAG);

  hipMemsetAsync(ws + OFF_SUMS, 0, 40, stream);                 // sums, std, cnt, pcnt
  hipMemsetAsync(ws + OFF_STD, 0xFF, 4, stream);                // 1/std sentinel
  hipMemsetAsync(ws + OFF_CSTAGE, 0xFF, (size_t)Bn * Gn * 3 * 4, stream);
  hipMemsetAsync(ws + OFF_GFLAG, 0, (size_t)Bn * Gn * 4, stream);
  mega_kernel<<<NB_FPS + NB_PREP + NB_KNN + NB_G1, 256, 0, stream>>>(
      points, outF, W1, Wa, Wb, feats, b1, W1b, Wab, Wbb, featb, rdenomTab,
      cstage, knn, cidx, diffb, sums, cnt, stdbits, pcnt, gflag, G1);
  gemm23_kernel<<<Mrows / 128, 512, 0, stream>>>(G1, Wab, ba, Wbb, bb, outF + Bn * Gn * 3);
}

// Round 15
// 652.673 us; speedup vs baseline: 1.6743x; 1.6743x over previous
//
#include <hip/hip_runtime.h>
#include <math.h>

// Problem constants
#define Bn   8
#define Nn   2048
#define Dn   192
#define Gn   512
#define Sn   32
#define OUTn 384
#define Mrows (Bn * Gn * Sn)

// megakernel block ranges
#define NB_FPS   8
#define NB_PREP  1680
#define NB_KNN   1024
#define NB_G1    3072          // 1024 bm x 3 bn
#define BLK_PREP (NB_FPS)                      // 8
#define BLK_KNN  (NB_FPS + NB_PREP)            // 1688
#define BLK_G1   (NB_FPS + NB_PREP + NB_KNN)   // 2712

typedef __attribute__((ext_vector_type(8))) unsigned short ushortx8;
typedef __attribute__((ext_vector_type(8))) __bf16 bf16x8;
typedef __attribute__((ext_vector_type(4))) float floatx4;

// ---------- ws layout (bytes) ----------
static constexpr size_t OFF_KNN    = 0;                    // 131072 * 4
static constexpr size_t OFF_CIDX   = 524288;               // 4096 * 4
static constexpr size_t OFF_DIFF   = 540672;               // 393216 * 4
static constexpr size_t OFF_SUMS   = 2113536;              // 2 doubles
static constexpr size_t OFF_STD    = 2113552;              // 1 u32 (1/std bits, 0xFF sentinel)
static constexpr size_t OFF_CNT    = 2113568;              // 1 int (knn done counter)
static constexpr size_t OFF_PCNT   = 2113572;              // 1 int (prep done counter)
static constexpr size_t OFF_DENOM  = 2113792;              // 64 floats (1/denom)
static constexpr size_t OFF_W1B    = 2114048;              // 147456 * 2
static constexpr size_t OFF_WAB    = 2408960;              // 73728 * 2
static constexpr size_t OFF_WBB    = 2556416;              // 73728 * 2
static constexpr size_t OFF_G1     = 2703872;              // 50331648 * 2
static constexpr size_t OFF_FEATB  = 103367168;            // 3145728 * 2 (bf16 feats)
static constexpr size_t OFF_CSTAGE = 109658624;            // 12288 * 4 (centers, 0xFF sentinel)
static constexpr size_t OFF_GFLAG  = 109707776;            // 4096 * 4 (knn group flags, 0)

__device__ __forceinline__ unsigned short f2bf(float f) {
  unsigned u = __float_as_uint(f);
  unsigned r = (u + 0x7FFFu + ((u >> 16) & 1u)) >> 16;   // RNE
  return (unsigned short)r;
}
__device__ __forceinline__ float bf2f(unsigned short h) {
  return __uint_as_float(((unsigned)h) << 16);
}
__device__ __forceinline__ floatx4 mfma_bf16(ushortx8 a, ushortx8 b, floatx4 c) {
  return __builtin_amdgcn_mfma_f32_16x16x32_bf16(
      __builtin_bit_cast(bf16x8, a), __builtin_bit_cast(bf16x8, b), c, 0, 0, 0);
}
__device__ __forceinline__ void gld16(const void* g, void* l) {
  __builtin_amdgcn_global_load_lds(
      (const __attribute__((address_space(1))) unsigned int*)g,
      (__attribute__((address_space(3))) unsigned int*)l, 16, 0, 0);
}
template <int CTRL>
__device__ __forceinline__ float dpp_max(float v) {
  int o = __builtin_amdgcn_update_dpp(0, __float_as_int(v), CTRL, 0xf, 0xf, true);
  return fmaxf(v, __int_as_float(o));
}
__device__ __forceinline__ void ast_u32(unsigned* p, unsigned v) {
  __hip_atomic_store(p, v, __ATOMIC_RELAXED, __HIP_MEMORY_SCOPE_AGENT);
}
__device__ __forceinline__ void ast_f32(float* p, float v) {
  __hip_atomic_store(p, v, __ATOMIC_RELAXED, __HIP_MEMORY_SCOPE_AGENT);
}
__device__ __forceinline__ unsigned ald_u32(const unsigned* p) {
  return __hip_atomic_load(p, __ATOMIC_RELAXED, __HIP_MEMORY_SCOPE_AGENT);
}

// ---------------------------------------------------------------------------
// MEGAKERNEL: fps (0-7) + prep (8..1687) + knn (1688..2711) + gemm1 (2712..
// 5783), overlapped via agent-scope sentinel/flag protocols (G16).
// r14 POST-MORTEM FIX: all spin-waits are RELAXED polls (no per-poll cache
// invalidation). r14 used ACQUIRE polls -> every poll emitted buffer_inv ->
// continuous chip-wide L1/L2 invalidation -> gemm1 smeared 7x (MfmaUtil 1.5%
// over 1020us = exactly gemm1's 38 GFLOP; VALUBusy 7.5%; HBM 170 GB/s of
// refetch). Ordering now: consumers poll relaxed, then issue ONE acquire
// load (per wave) before reading protected data. Sentinel words whose value
// IS the payload (centers, 1/std) need no fence at all (r13-proven).
// Deadlock-free under in-order dispatch (deps point to earlier blocks only).
// All arithmetic bit-identical to prior rounds.
// ---------------------------------------------------------------------------
__global__ __launch_bounds__(256) void mega_kernel(
    const float* __restrict__ points, float* __restrict__ centers,
    const float* __restrict__ W1, const float* __restrict__ Wa,
    const float* __restrict__ Wb, const float* __restrict__ feats,
    const float* __restrict__ b1,
    unsigned short* __restrict__ W1b, unsigned short* __restrict__ Wab,
    unsigned short* __restrict__ Wbb, unsigned short* __restrict__ featb,
    float* __restrict__ rdenomTab, float* __restrict__ cstage,
    int* __restrict__ knn, int* __restrict__ cidx, float* __restrict__ diffb,
    double* __restrict__ sums, int* __restrict__ cnt, unsigned* __restrict__ stdbits,
    unsigned* __restrict__ pcnt, unsigned* __restrict__ gflag,
    unsigned short* __restrict__ G1) {
  const int t = threadIdx.x;
  const int w = t >> 6, lane = t & 63;
  const int blk = blockIdx.x;
  __shared__ __align__(16) char smem[32832];

  // ======================= PREP path =======================
  if (blk >= BLK_PREP && blk < BLK_KNN) {
    unsigned* W1b32 = (unsigned*)W1b;
    unsigned* Wab32 = (unsigned*)Wab;
    unsigned* Wbb32 = (unsigned*)Wbb;
    unsigned* fb32  = (unsigned*)featb;
    const int base = (blk - BLK_PREP) * 1024 + t;
#pragma unroll
    for (int j = 0; j < 4; ++j) {
      const int i = base + j * 256;     // u32 index, < 1720320 by grid
      const float* src; unsigned* dst; int k;
      if (i < 73728)       { src = W1;    dst = W1b32; k = i; }
      else if (i < 110592) { src = Wa;    dst = Wab32; k = i - 73728; }
      else if (i < 147456) { src = Wb;    dst = Wbb32; k = i - 110592; }
      else                 { src = feats; dst = fb32;  k = i - 147456; }
      const unsigned lo = f2bf(src[2 * k]);
      const unsigned hi = f2bf(src[2 * k + 1]);
      ast_u32(dst + k, lo | (hi << 16));
    }
    if (blk == BLK_PREP && t < 64)
      ast_f32(rdenomTab + t, (float)(1.0 / pow(1000.0, (double)t / 64.0)));
    __syncthreads();
    if (t == 0) {
      __threadfence();
      __hip_atomic_fetch_add(pcnt, 1u, __ATOMIC_RELEASE, __HIP_MEMORY_SCOPE_AGENT);
    }
    return;
  }

  // ======================= KNN path =======================
  if (blk >= BLK_KNN && blk < BLK_G1) {
    const int bg = (blk - BLK_KNN) * 4 + w;
    const int b = bg >> 9;
    const float* P = points + (size_t)b * Nn * 3;
    const unsigned* cs = (const unsigned*)(cstage + (size_t)bg * 3);

    unsigned ux, uy, uz;
    for (;;) {        // RELAXED polls: the words ARE the payload (r13-proven)
      ux = ald_u32(cs + 0); uy = ald_u32(cs + 1); uz = ald_u32(cs + 2);
      if (ux != 0xFFFFFFFFu && uy != 0xFFFFFFFFu && uz != 0xFFFFFFFFu) break;
      __builtin_amdgcn_s_sleep(16);
    }
    const float cx = __uint_as_float(ux);
    const float cy = __uint_as_float(uy);
    const float cz = __uint_as_float(uz);
    const float aa = __fadd_rn(__fadd_rn(__fmul_rn(cx, cx), __fmul_rn(cy, cy)), __fmul_rn(cz, cz));

    unsigned key[32];
#pragma unroll 8
    for (int s = 0; s < 32; ++s) {
      const int n = s * 64 + lane;
      float X = P[n * 3], Y = P[n * 3 + 1], Z = P[n * 3 + 2];
      float bbv = __fadd_rn(__fadd_rn(__fmul_rn(X, X), __fmul_rn(Y, Y)), __fmul_rn(Z, Z));
      float dot = __fadd_rn(__fadd_rn(__fmul_rn(cx, X), __fmul_rn(cy, Y)), __fmul_rn(cz, Z));
      float d2 = __fsub_rn(__fadd_rn(aa, bbv), __fmul_rn(2.0f, dot));
      unsigned u = __float_as_uint(d2);
      key[s] = u ^ ((unsigned)((int)u >> 31) | 0x80000000u);
    }
    unsigned mk = key[0]; int ms = 0;
#pragma unroll
    for (int s = 1; s < 32; ++s)
      if (key[s] < mk) { mk = key[s]; ms = s; }

    int mysel = 0;
    for (int it = 0; it < Sn; ++it) {
      unsigned long long p = ((unsigned long long)mk << 32) | (unsigned)(ms * 64 + lane);
#pragma unroll
      for (int off = 1; off <= 32; off <<= 1) {
        unsigned long long o = __shfl_xor(p, off, 64);
        p = (o < p) ? o : p;
      }
      const int n_win = (int)(unsigned)p;
      if (lane == it) mysel = n_win;
      if (lane == (n_win & 63)) {
        const int sw = n_win >> 6;
#pragma unroll
        for (int s = 0; s < 32; ++s)
          if (s == sw) key[s] = 0xFFFFFFFFu;
        mk = key[0]; ms = 0;
#pragma unroll
        for (int s = 1; s < 32; ++s)
          if (key[s] < mk) { mk = key[s]; ms = s; }
      }
    }

    double s1 = 0.0, s2 = 0.0;
    if (lane < Sn) {
      ast_u32((unsigned*)&knn[(size_t)bg * Sn + lane], (unsigned)mysel);
      float X = P[mysel * 3], Y = P[mysel * 3 + 1], Z = P[mysel * 3 + 2];
      float dx = __fsub_rn(X, cx), dy = __fsub_rn(Y, cy), dz = __fsub_rn(Z, cz);
      float* db = diffb + (size_t)bg * 96 + lane * 3;
      ast_f32(db + 0, dx); ast_f32(db + 1, dy); ast_f32(db + 2, dz);
      s1 = (double)dx + (double)dy + (double)dz;
      s2 = (double)dx * (double)dx + (double)dy * (double)dy + (double)dz * (double)dz;
    }
#pragma unroll
    for (int off = 1; off <= 32; off <<= 1) {
      s1 += __shfl_xor(s1, off, 64);
      s2 += __shfl_xor(s2, off, 64);
    }
    if (lane == 0) {
      ast_u32((unsigned*)&cidx[bg], (unsigned)__shfl(mysel, 0, 64));
      atomicAdd(sums, s1);
      atomicAdd(sums + 1, s2);
      // RELEASE: per-wave vmcnt drain orders this wave's data stores first
      __hip_atomic_store(&gflag[bg], 1u, __ATOMIC_RELEASE, __HIP_MEMORY_SCOPE_AGENT);
    }
    __threadfence();
    __syncthreads();
    if (t == 0) {
      const int old = atomicAdd(cnt, 1);
      if (old == NB_KNN - 1) {          // last knn block: publish 1/(std+eps)
        __threadfence();
        const double S1 = atomicAdd(sums, 0.0);
        const double S2 = atomicAdd(sums + 1, 0.0);
        const double n = (double)(Bn * Gn * Sn * 3);
        const double mean = S1 / n;
        const double var = (S2 - S1 * mean) / (n - 1.0);
        const float stdf = (float)sqrt(var) + 1e-5f;
        const float rstdv = (float)(1.0 / (double)stdf);
        __hip_atomic_store(stdbits, __float_as_uint(rstdv), __ATOMIC_RELEASE,
                           __HIP_MEMORY_SCOPE_AGENT);
      }
    }
    return;
  }

  // ======================= GEMM1 path =======================
  if (blk >= BLK_G1) {
    const int gb = blk - BLK_G1;
    const int bm = gb & 1023, bn = gb >> 10;
    unsigned short* As = (unsigned short*)smem;
    unsigned short* Bs = (unsigned short*)(smem + 16384);
    const int wid = w, quad = lane >> 4, c16 = lane & 15;
    const int wr = wid >> 1, wc = wid & 1;

    // RELAXED polls (no invalidation per poll — the r14 fix), then ONE
    // acquire load to order subsequent reads of knn/diffb/cidx/W1b/featb.
    while (ald_u32(pcnt) < (unsigned)NB_PREP)
      __builtin_amdgcn_s_sleep(32);
#pragma unroll
    for (int g = 0; g < 4; ++g)
      while (ald_u32(&gflag[bm * 4 + g]) == 0u)
        __builtin_amdgcn_s_sleep(16);
    (void)__hip_atomic_load(&gflag[bm * 4], __ATOMIC_ACQUIRE, __HIP_MEMORY_SCOPE_AGENT);

    int aOffN[4], aOffC[4], bOff[4];
#pragma unroll
    for (int i = 0; i < 4; ++i) {
      const int slot = i * 256 + t;
      const int row = slot >> 3, segV = slot & 7;
      const int seg = segV ^ (row & 7);
      const int grow = bm * 128 + row;
      const int bg = grow >> 5, s = grow & 31, bb_ = bg >> 9;
      const int nidx = knn[(size_t)bg * Sn + s];
      const int ci = (int)ald_u32((const unsigned*)&cidx[bg]);
      aOffN[i] = (bb_ * Nn + nidx) * Dn + seg * 8;
      aOffC[i] = (bb_ * Nn + ci) * Dn + seg * 8;
      bOff[i] = (bn * 128 + row) * 384 + seg * 8;
    }

    floatx4 acc[4][4];
#pragma unroll
    for (int i = 0; i < 4; ++i)
#pragma unroll
      for (int j = 0; j < 4; ++j) acc[i][j] = (floatx4){0.f, 0.f, 0.f, 0.f};

    for (int kt = 0; kt < 6; ++kt) {
      const int kb = kt * 64;
#pragma unroll
      for (int i = 0; i < 4; ++i) {
        const unsigned short* srcA =
            (kt < 3) ? (featb + aOffN[i] + kb) : (featb + aOffC[i] + (kb - 192));
        gld16(srcA, &As[(i * 256 + wid * 64) * 8]);
        gld16(W1b + bOff[i] + kb, &Bs[(i * 256 + wid * 64) * 8]);
      }
      __syncthreads();
#pragma unroll
      for (int ks = 0; ks < 2; ++ks) {
        ushortx8 af[4], bf[4];
#pragma unroll
        for (int mt = 0; mt < 4; ++mt) {
          const int row = wr * 64 + mt * 16 + c16;
          const int seg = (ks * 4 + quad) ^ (row & 7);
          af[mt] = *(const ushortx8*)&As[row * 64 + seg * 8];
        }
#pragma unroll
        for (int nt = 0; nt < 4; ++nt) {
          const int row = wc * 64 + nt * 16 + c16;
          const int seg = (ks * 4 + quad) ^ (row & 7);
          bf[nt] = *(const ushortx8*)&Bs[row * 64 + seg * 8];
        }
#pragma unroll
        for (int mt = 0; mt < 4; ++mt)
#pragma unroll
          for (int nt = 0; nt < 4; ++nt)
            acc[mt][nt] = mfma_bf16(af[mt], bf[nt], acc[mt][nt]);
      }
      __syncthreads();
    }

    // 1/std: RELAXED poll — the sentinel word IS the payload (no fence).
    unsigned sb;
    for (;;) {
      sb = ald_u32(stdbits);
      if (sb != 0xFFFFFFFFu) break;
      __builtin_amdgcn_s_sleep(16);
    }
    const float rstd = __uint_as_float(sb);

    float bias[4], rdnm[4];
    bool usin[4];
#pragma unroll
    for (int nt = 0; nt < 4; ++nt) {
      const int col = bn * 128 + wc * 64 + nt * 16 + c16;
      bias[nt] = b1[col];
      const int j = col & 127;
      usin[nt] = (j < 64);
      rdnm[nt] = rdenomTab[j & 63];
    }
#pragma unroll
    for (int mt = 0; mt < 4; ++mt) {
#pragma unroll
      for (int r = 0; r < 4; ++r) {
        const int row = bm * 128 + wr * 64 + mt * 16 + quad * 4 + r;
        const float dv = diffb[(size_t)row * 3 + bn];
        const float x = __fmul_rn(dv, rstd);
        const float zb = __fmul_rn(100.0f, x);
#pragma unroll
        for (int nt = 0; nt < 4; ++nt) {
          const int col = bn * 128 + wc * 64 + nt * 16 + c16;
          float y = fmaxf(acc[mt][nt][r] + bias[nt], 0.f);
          float z = __fmul_rn(zb, rdnm[nt]);
          float p = usin[nt] ? __sinf(z) : __cosf(z);
          float g = (y + p) * p;
          G1[(size_t)row * 384 + col] = f2bf(g);
        }
      }
    }
    return;
  }

  // ======================= FPS path (blocks 0-7) =======================
  const int b = blk;
  float4* p4 = (float4*)smem;
  unsigned long long* wkey = (unsigned long long*)(smem + 32768);  // [2][4]

  const float* P = points + (size_t)b * Nn * 3;
  for (int n = t; n < Nn; n += 256) {
    float x = P[n * 3], y = P[n * 3 + 1], z = P[n * 3 + 2];
    p4[n] = make_float4(x, y, z, 0.f);
  }
  __syncthreads();

  float rx[8], ry[8], rz[8], dist[8];
#pragma unroll
  for (int k = 0; k < 8; ++k) {
    float4 p = p4[t * 8 + k];       // LDS source -> VGPR-resident (r5/r10/r12)
    rx[k] = p.x; ry[k] = p.y; rz[k] = p.z;
    dist[k] = INFINITY;
  }

  int cur = 0;
  for (int it = 0; it < Gn; ++it) {
    const float4 c = p4[cur];
    if (t == 0) {
      float* cd = centers + ((size_t)b * Gn + it) * 3;
      cd[0] = c.x; cd[1] = c.y; cd[2] = c.z;
      unsigned* cs = (unsigned*)(cstage + ((size_t)b * Gn + it) * 3);
      ast_u32(cs + 0, __float_as_uint(c.x));
      ast_u32(cs + 1, __float_as_uint(c.y));
      ast_u32(cs + 2, __float_as_uint(c.z));
    }
    float bv = -1.0f;
#pragma unroll
    for (int k = 0; k < 8; ++k) {
      float dx = __fsub_rn(rx[k], c.x);
      float dy = __fsub_rn(ry[k], c.y);
      float dz = __fsub_rn(rz[k], c.z);
      float d = __fadd_rn(__fadd_rn(__fmul_rn(dx, dx), __fmul_rn(dy, dy)), __fmul_rn(dz, dz));
      dist[k] = fminf(dist[k], d);
      bv = fmaxf(bv, dist[k]);
    }
    int li = 7;
#pragma unroll
    for (int k = 6; k >= 0; --k) li = (dist[k] == bv) ? k : li;

    float red = bv;
    red = dpp_max<0x111>(red);
    red = dpp_max<0x112>(red);
    red = dpp_max<0x114>(red);
    red = dpp_max<0x118>(red);
    red = dpp_max<0x142>(red);
    red = dpp_max<0x143>(red);
    const float M = __int_as_float(__builtin_amdgcn_readlane(__float_as_int(red), 63));

    unsigned long long msk = __ballot(bv == M);
    const int L = __ffsll((long long)msk) - 1;
    const int liL = __builtin_amdgcn_readlane(li, L);
    const int idx = (w * 64 + L) * 8 + liL;

    unsigned long long key =
        ((unsigned long long)__float_as_uint(M) << 32) | (unsigned)(0x7FFFFFFF - idx);
    if (lane == 0) wkey[(it & 1) * 4 + w] = key;
    __syncthreads();
    unsigned long long k0 = wkey[(it & 1) * 4 + 0];
    unsigned long long k1 = wkey[(it & 1) * 4 + 1];
    unsigned long long k2 = wkey[(it & 1) * 4 + 2];
    unsigned long long k3 = wkey[(it & 1) * 4 + 3];
    unsigned long long m01 = (k1 > k0) ? k1 : k0;
    unsigned long long m23 = (k3 > k2) ? k3 : k2;
    unsigned long long mm = (m23 > m01) ? m23 : m01;
    cur = 0x7FFFFFFF - (int)(unsigned)mm;
  }
}

// ===========================================================================
// GEMM23 (fused residual block) — r9-measured version, unchanged.
// ===========================================================================
__global__ __launch_bounds__(512) void gemm23_kernel(
    const unsigned short* __restrict__ G1, const unsigned short* __restrict__ Wab,
    const float* __restrict__ ba, const unsigned short* __restrict__ Wbb,
    const float* __restrict__ bb, float* __restrict__ outp) {
  __shared__ __align__(16) char smem[100352];
  unsigned short* Htile = (unsigned short*)smem;                  // 128 x 200
  unsigned short* As    = (unsigned short*)(smem + 51200);        // 128 x 64
  unsigned short* BsA   = (unsigned short*)(smem + 51200 + 16384);// 192 x 64
  unsigned short* BsB   = (unsigned short*)(smem + 51200);        // 384 x 64 (aliases)

  const int t = threadIdx.x;
  const int bm = blockIdx.x;
  const int lane = t & 63, quad = lane >> 4, c16 = lane & 15;
  const int wid = t >> 6;
  const int wr = wid >> 2, wc = wid & 3;    // 2 x 4 wave grid

  int aOff[2], bOffA[3];
#pragma unroll
  for (int i = 0; i < 2; ++i) {
    const int slot = i * 512 + t;
    const int row = slot >> 3, segV = slot & 7;
    aOff[i] = (bm * 128 + row) * 384 + (segV ^ (row & 7)) * 8;
  }
#pragma unroll
  for (int i = 0; i < 3; ++i) {
    const int slot = i * 512 + t;
    const int row = slot >> 3, segV = slot & 7;
    bOffA[i] = row * 384 + (segV ^ (row & 7)) * 8;
  }

  floatx4 accA[4][3];
#pragma unroll
  for (int i = 0; i < 4; ++i)
#pragma unroll
    for (int j = 0; j < 3; ++j) accA[i][j] = (floatx4){0.f, 0.f, 0.f, 0.f};

  for (int kt = 0; kt < 6; ++kt) {
    const int kb = kt * 64;
#pragma unroll
    for (int i = 0; i < 2; ++i) gld16(G1 + aOff[i] + kb, As + ((size_t)(i * 512 + t)) * 8);
#pragma unroll
    for (int i = 0; i < 3; ++i) gld16(Wab + bOffA[i] + kb, BsA + ((size_t)(i * 512 + t)) * 8);
    __syncthreads();
#pragma unroll
    for (int ks = 0; ks < 2; ++ks) {
      ushortx8 af[4], bf[3];
#pragma unroll
      for (int mt = 0; mt < 4; ++mt) {
        const int row = wr * 64 + mt * 16 + c16;
        const int seg = (ks * 4 + quad) ^ (row & 7);
        af[mt] = *(const ushortx8*)&As[row * 64 + seg * 8];
      }
#pragma unroll
      for (int nt = 0; nt < 3; ++nt) {
        const int row = wc * 48 + nt * 16 + c16;
        const int seg = (ks * 4 + quad) ^ (row & 7);
        bf[nt] = *(const ushortx8*)&BsA[row * 64 + seg * 8];
      }
#pragma unroll
      for (int mt = 0; mt < 4; ++mt)
#pragma unroll
        for (int nt = 0; nt < 3; ++nt)
          accA[mt][nt] = mfma_bf16(af[mt], bf[nt], accA[mt][nt]);
    }
    __syncthreads();
  }

#pragma unroll
  for (int nt = 0; nt < 3; ++nt) {
    const int col = wc * 48 + nt * 16 + c16;
    const float bias = ba[col];
#pragma unroll
    for (int mt = 0; mt < 4; ++mt)
#pragma unroll
      for (int r = 0; r < 4; ++r) {
        const int row = wr * 64 + mt * 16 + quad * 4 + r;
        Htile[row * 200 + col] = f2bf(fmaxf(accA[mt][nt][r] + bias, 0.f));
      }
  }
  __syncthreads();

  int bOffB[6];
#pragma unroll
  for (int i = 0; i < 6; ++i) {
    const int slot = i * 512 + t;
    const int row = slot >> 3, segV = slot & 7;
    bOffB[i] = row * 192 + (segV ^ (row & 7)) * 8;
  }

  floatx4 acc[4][6];
#pragma unroll
  for (int i = 0; i < 4; ++i)
#pragma unroll
    for (int j = 0; j < 6; ++j) acc[i][j] = (floatx4){0.f, 0.f, 0.f, 0.f};

  for (int kt = 0; kt < 3; ++kt) {
    const int kb = kt * 64;
#pragma unroll
    for (int i = 0; i < 6; ++i) gld16(Wbb + bOffB[i] + kb, BsB + ((size_t)(i * 512 + t)) * 8);
    __syncthreads();
#pragma unroll
    for (int ks = 0; ks < 2; ++ks) {
      ushortx8 af[4], bf[6];
#pragma unroll
      for (int mt = 0; mt < 4; ++mt) {
        const int row = wr * 64 + mt * 16 + c16;
        af[mt] = *(const ushortx8*)&Htile[row * 200 + kb + ks * 32 + quad * 8];
      }
#pragma unroll
      for (int nt = 0; nt < 6; ++nt) {
        const int row = wc * 96 + nt * 16 + c16;
        const int seg = (ks * 4 + quad) ^ (row & 7);
        bf[nt] = *(const ushortx8*)&BsB[row * 64 + seg * 8];
      }
#pragma unroll
      for (int mt = 0; mt < 4; ++mt)
#pragma unroll
        for (int nt = 0; nt < 6; ++nt)
          acc[mt][nt] = mfma_bf16(af[mt], bf[nt], acc[mt][nt]);
    }
    __syncthreads();
  }

#pragma unroll
  for (int nt = 0; nt < 6; ++nt) {
    const int col = wc * 96 + nt * 16 + c16;
    const float bias = bb[col];
    float gmax[2] = {-INFINITY, -INFINITY};
    float gsum[2] = {0.f, 0.f};
#pragma unroll
    for (int mt = 0; mt < 4; ++mt) {
      const int grp = mt >> 1;
#pragma unroll
      for (int r = 0; r < 4; ++r) {
        const int row = bm * 128 + wr * 64 + mt * 16 + quad * 4 + r;
        float v = acc[mt][nt][r] + bias + bf2f(G1[(size_t)row * 384 + col]);
        v = fmaxf(v, 0.f);
        gmax[grp] = fmaxf(gmax[grp], v);
        gsum[grp] += v;
      }
    }
#pragma unroll
    for (int grp = 0; grp < 2; ++grp) {
      float m = gmax[grp], su = gsum[grp];
#pragma unroll
      for (int off = 16; off <= 32; off <<= 1) {
        m = fmaxf(m, __shfl_xor(m, off, 64));
        su += __shfl_xor(su, off, 64);
      }
      if (quad == 0) {
        const int bg = bm * 4 + wr * 2 + grp;
        outp[(size_t)bg * 384 + col] = m + su / 32.0f;
      }
    }
  }
}

// ---------------------------------------------------------------------------
extern "C" void kernel_launch(void* const* d_in, const int* in_sizes, int n_in,
                              void* d_out, int out_size, void* d_ws, size_t ws_size,
                              hipStream_t stream) {
  const float* points = (const float*)d_in[0];
  const float* feats  = (const float*)d_in[1];
  const float* W1 = (const float*)d_in[2];
  const float* b1 = (const float*)d_in[3];
  const float* Wa = (const float*)d_in[4];
  const float* ba = (const float*)d_in[5];
  const float* Wb = (const float*)d_in[6];
  const float* bb = (const float*)d_in[7];
  float* outF = (float*)d_out;

  char* ws = (char*)d_ws;
  int*            knn      = (int*)(ws + OFF_KNN);
  int*            cidx     = (int*)(ws + OFF_CIDX);
  float*          diffb    = (float*)(ws + OFF_DIFF);
  double*         sums     = (double*)(ws + OFF_SUMS);
  unsigned*       stdbits  = (unsigned*)(ws + OFF_STD);
  int*            cnt      = (int*)(ws + OFF_CNT);
  unsigned*       pcnt     = (unsigned*)(ws + OFF_PCNT);
  float*          rdenomTab= (float*)(ws + OFF_DENOM);
  unsigned short* W1b      = (unsigned short*)(ws + OFF_W1B);
  unsigned short* Wab      = (unsigned short*)(ws + OFF_WAB);
  unsigned short* Wbb      = (unsigned short*)(ws + OFF_WBB);
  unsigned short* G1       = (unsigned short*)(ws + OFF_G1);
  unsigned short* featb    = (unsigned short*)(ws + OFF_FEATB);
  float*          cstage   = (float*)(ws + OFF_CSTAGE);
  unsigned*       gflag    = (unsigned*)(ws + OFF_GFLAG);

  hipMemsetAsync(ws + OFF_SUMS, 0, 40, stream);                 // sums, std, cnt, pcnt
  hipMemsetAsync(ws + OFF_STD, 0xFF, 4, stream);                // 1/std sentinel
  hipMemsetAsync(ws + OFF_CSTAGE, 0xFF, (size_t)Bn * Gn * 3 * 4, stream);
  hipMemsetAsync(ws + OFF_GFLAG, 0, (size_t)Bn * Gn * 4, stream);
  mega_kernel<<<NB_FPS + NB_PREP + NB_KNN + NB_G1, 256, 0, stream>>>(
      points, outF, W1, Wa, Wb, feats, b1, W1b, Wab, Wbb, featb, rdenomTab,
      cstage, knn, cidx, diffb, sums, cnt, stdbits, pcnt, gflag, G1);
  gemm23_kernel<<<Mrows / 128, 512, 0, stream>>>(G1, Wab, ba, Wbb, bb, outF + Bn * Gn * 3);
}